// Round 2
// baseline (141.321 us; speedup 1.0000x reference)
//
#include <hip/hip_runtime.h>

#define D 256
#define NV 512   // v_alpha rows
#define NT 512   // t_alpha rows
#define EPS 1e-8f

// lgamma(x) for x > 0 (tuned for x in (0, 1.1]): shift by 4 then Stirling.
__device__ __forceinline__ float fast_lgamma_small(float x) {
    float p  = x * (x + 1.0f) * (x + 2.0f) * (x + 3.0f);
    float y  = x + 4.0f;
    float ly = __logf(y);
    float lp = __logf(p);
    float r  = __builtin_amdgcn_rcpf(y);
    float r2 = r * r;
    float tail = r * (0.0833333333f - 0.0027777778f * r2);
    return (y - 0.5f) * ly - y + 0.91893853f + tail - lp;
}

// digamma(x) for x > 0 small; exact-division pole terms dominate accuracy.
__device__ __forceinline__ float fast_digamma_small(float x) {
    float y  = x + 4.0f;
    float r  = 1.0f / y;
    float r2 = r * r;
    float psi = __logf(y) - 0.5f * r - r2 * (0.0833333333f - 0.0083333333f * r2);
    return psi - 1.0f / x - 1.0f / (x + 1.0f) - 1.0f / (x + 2.0f) - 1.0f / (x + 3.0f);
}

__device__ __forceinline__ float stirling_lgamma(float y) { // y >= 4
    float r  = 1.0f / y;
    float r2 = r * r;
    return (y - 0.5f) * __logf(y) - y + 0.91893853f
         + r * (0.0833333333f - 0.0027777778f * r2);
}

__device__ __forceinline__ float stirling_digamma(float y) { // y >= 4
    float r  = 1.0f / y;
    float r2 = r * r;
    return __logf(y) - 0.5f * r - r2 * (0.0833333333f - 0.0083333333f * r2);
}

// One block per row (N + M blocks). Writes digamma row + 5 scalars.
__global__ __launch_bounds__(256) void row_stats(
    const float* __restrict__ va, const float* __restrict__ ta,
    float* __restrict__ dgv, float* __restrict__ dgt,
    float* __restrict__ rv,  float* __restrict__ rt)
{
    int r = blockIdx.x;
    const float* row; float* dgrow; float* sc;
    if (r < NV) { row = va + r * D; dgrow = dgv + r * D; sc = rv + r * 8; }
    else { int q = r - NV; row = ta + q * D; dgrow = dgt + q * D; sc = rt + q * 8; }

    int d = threadIdx.x;                 // 256 threads = D
    float raw = row[d];
    float x = raw + EPS;
    float g  = fast_lgamma_small(x);
    float dg = fast_digamma_small(x);
    dgrow[d] = dg;

    float S = raw, G = g, P = raw * dg;
    #pragma unroll
    for (int off = 32; off > 0; off >>= 1) {
        S += __shfl_down(S, off, 64);
        G += __shfl_down(G, off, 64);
        P += __shfl_down(P, off, 64);
    }
    __shared__ float red[3][4];
    int wid = d >> 6, lane = d & 63;
    if (lane == 0) { red[0][wid] = S; red[1][wid] = G; red[2][wid] = P; }
    __syncthreads();
    if (d == 0) {
        float S4 = red[0][0] + red[0][1] + red[0][2] + red[0][3];
        float G4 = red[1][0] + red[1][1] + red[1][2] + red[1][3];
        float P4 = red[2][0] + red[2][1] + red[2][2] + red[2][3];
        float Se = S4 + 256.0f * EPS;    // sum includes per-element eps
        sc[0] = S4; sc[1] = G4; sc[2] = P4;
        sc[3] = stirling_lgamma(Se);
        sc[4] = stirling_digamma(Se);
    }
}

// 16x16 output tile per block; v,t,psi(v),psi(t) tiles in LDS (64 KiB exactly),
// XOR-(row&7) swizzle on float4 columns to kill stride-1024B bank conflicts.
__global__ __launch_bounds__(256) void jsd_pairs(
    const float* __restrict__ va, const float* __restrict__ ta,
    const float* __restrict__ dgv, const float* __restrict__ dgt,
    const float* __restrict__ rv,  const float* __restrict__ rt,
    float* __restrict__ out)
{
    __shared__ float vs[16 * 256];
    __shared__ float ts[16 * 256];
    __shared__ float gv[16 * 256];
    __shared__ float gt[16 * 256];

    const int tid = threadIdx.x;
    const int j0 = blockIdx.x * 16;      // v-tile (output cols, contiguous)
    const int i0 = blockIdx.y * 16;      // t-tile (output rows)

    #pragma unroll
    for (int k = 0; k < 4; ++k) {
        int q   = tid + (k << 8);
        int row = q >> 6;                // 0..15
        int c   = q & 63;                // float4 column 0..63
        int cs  = c ^ (row & 7);         // swizzled physical column
        float4 a = *(const float4*)(va  + (j0 + row) * D + (c << 2));
        float4 b = *(const float4*)(dgv + (j0 + row) * D + (c << 2));
        float4 e = *(const float4*)(ta  + (i0 + row) * D + (c << 2));
        float4 f = *(const float4*)(dgt + (i0 + row) * D + (c << 2));
        *(float4*)(vs + row * 256 + (cs << 2)) = a;
        *(float4*)(gv + row * 256 + (cs << 2)) = b;
        *(float4*)(ts + row * 256 + (cs << 2)) = e;
        *(float4*)(gt + row * 256 + (cs << 2)) = f;
    }
    __syncthreads();

    const int tj = tid & 15;             // output col within tile
    const int ti = tid >> 4;             // output row within tile
    const float* vrow = vs + tj * 256;
    const float* grow = gv + tj * 256;
    const float* trow = ts + ti * 256;
    const float* hrow = gt + ti * 256;
    const int swv = tj & 7;
    const int swt = ti & 7;

    float accg = 0.0f, xvt = 0.0f, xtv = 0.0f;
    #pragma unroll 4
    for (int c = 0; c < 64; ++c) {
        int cv = (c ^ swv) << 2;
        int ct = (c ^ swt) << 2;
        float4 v4 = *(const float4*)(vrow + cv);
        float4 g4 = *(const float4*)(grow + cv);
        float4 t4 = *(const float4*)(trow + ct);
        float4 h4 = *(const float4*)(hrow + ct);

        accg += fast_lgamma_small(0.5f * (v4.x + t4.x) + EPS);
        accg += fast_lgamma_small(0.5f * (v4.y + t4.y) + EPS);
        accg += fast_lgamma_small(0.5f * (v4.z + t4.z) + EPS);
        accg += fast_lgamma_small(0.5f * (v4.w + t4.w) + EPS);

        xvt += t4.x * g4.x + t4.y * g4.y + t4.z * g4.z + t4.w * g4.w;
        xtv += v4.x * h4.x + v4.y * h4.y + v4.z * h4.z + v4.w * h4.w;
    }

    const int j = j0 + tj, i = i0 + ti;
    const float* rj = rv + j * 8;
    const float* ri = rt + i * 8;
    float Sv = rj[0], Gv = rj[1], Pv = rj[2], glSv = rj[3], dgSv = rj[4];
    float St = ri[0], Gt = ri[1], Pt = ri[2], glSt = ri[3], dgSt = ri[4];

    float Sm  = 0.5f * (Sv + St) + 256.0f * EPS;
    float jsd = accg - stirling_lgamma(Sm)
              + 0.5f  * ((glSv - Gv) + (glSt - Gt))
              + 0.25f * ((Pv - xvt) + (Pt - xtv))
              + 0.25f * (Sv - St) * (dgSt - dgSv);

    out[i * 512 + j] = 1.0f - jsd;
}

extern "C" void kernel_launch(void* const* d_in, const int* in_sizes, int n_in,
                              void* d_out, int out_size, void* d_ws, size_t ws_size,
                              hipStream_t stream) {
    const float* va = (const float*)d_in[0];   // (512, 256) f32
    const float* ta = (const float*)d_in[1];   // (512, 256) f32
    float* ws  = (float*)d_ws;
    float* dgv = ws;                           // 512*256
    float* dgt = ws + NV * D;                  // 512*256
    float* rv  = ws + (NV + NT) * D;           // 512*8
    float* rt  = rv + NV * 8;                  // 512*8
    float* out = (float*)d_out;                // (512, 512) f32

    row_stats<<<NV + NT, 256, 0, stream>>>(va, ta, dgv, dgt, rv, rt);
    jsd_pairs<<<dim3(32, 32), 256, 0, stream>>>(va, ta, dgv, dgt, rv, rt, out);
}

// Round 3
// 85.619 us; speedup vs baseline: 1.6506x; 1.6506x over previous
//
#include <hip/hip_runtime.h>

#define D 256
#define NV 512
#define NT 512
#define EPS 1e-8f
#define LN2 0.69314718055994531f

// Taylor of lgamma(x) at x0 = 2.5 (s = x - 2.5), |err| <= 3e-6 for x in [2,3].
// Used as lgamma(m) = poly(m - 0.5) - ln(m*(m+1)), m in (0, 1].
#define C0 0.28468287047291920f
#define C1 0.70315664064524320f
#define C2 0.24517887805011740f
#define C3 (-0.03936734194028790f)
#define C4 0.00932941036738560f
#define C5 (-0.00261463332905590f)
#define C6 0.00080356830356760f

__device__ __forceinline__ float rcpf(float x) { return __builtin_amdgcn_rcpf(x); }

__device__ __forceinline__ float lgamma_poly(float s) { // s = x - 0.5, x in (0,1]
    float q = fmaf(C6, s, C5);
    q = fmaf(q, s, C4); q = fmaf(q, s, C3); q = fmaf(q, s, C2); q = fmaf(q, s, C1);
    return q; // caller: lgamma = fmaf(q, s, C0) - ln(x*(x+1))
}

__device__ __forceinline__ float stirling_lgamma(float y) { // y >= 4
    float r = rcpf(y), r2 = r * r;
    float ln = LN2 * __log2f(y);
    return (y - 0.5f) * ln - y + 0.91893853320467f
         + r * (0.08333333333f - 0.00277777778f * r2);
}

__device__ __forceinline__ float stirling_digamma(float y) { // y >= 4
    float r = rcpf(y), r2 = r * r;
    return LN2 * __log2f(y) - 0.5f * r - r2 * (0.08333333333f - 0.00833333333f * r2);
}

// One block per row. Writes digamma row + packed float4 [S, A, dgS, 0],
// A = 0.5*(lgamma(S') - sum lgamma(x')) + 0.25 * sum raw*psi(x').
__global__ __launch_bounds__(256) void row_stats(
    const float* __restrict__ va, const float* __restrict__ ta,
    float* __restrict__ dgv, float* __restrict__ dgt,
    float* __restrict__ rv,  float* __restrict__ rt)
{
    int r = blockIdx.x;
    const float* row; float* dgrow; float* sc;
    if (r < NV) { row = va + r * D; dgrow = dgv + r * D; sc = rv + r * 4; }
    else { int q = r - NV; row = ta + q * D; dgrow = dgt + q * D; sc = rt + q * 4; }

    int d = threadIdx.x;
    float raw = row[d];
    float x = raw + EPS;

    // digamma(x) = psi(x+4) - sum of 4 poles (v_rcp, headroom covers 1e-7 rel)
    float y = x + 4.0f;
    float ry = rcpf(y), ry2 = ry * ry;
    float psi = LN2 * __log2f(y) - 0.5f * ry - ry2 * (0.08333333333f - 0.00833333333f * ry2);
    psi -= rcpf(x) + rcpf(x + 1.0f) + rcpf(x + 2.0f) + rcpf(x + 3.0f);
    dgrow[d] = psi;

    float s = x - 0.5f;
    float g = fmaf(lgamma_poly(s), s, C0) - LN2 * __log2f(x * (x + 1.0f));

    float S = raw, G = g, P = raw * psi;
    #pragma unroll
    for (int off = 32; off > 0; off >>= 1) {
        S += __shfl_down(S, off, 64);
        G += __shfl_down(G, off, 64);
        P += __shfl_down(P, off, 64);
    }
    __shared__ float red[3][4];
    int wid = d >> 6, lane = d & 63;
    if (lane == 0) { red[0][wid] = S; red[1][wid] = G; red[2][wid] = P; }
    __syncthreads();
    if (d == 0) {
        float S4 = red[0][0] + red[0][1] + red[0][2] + red[0][3];
        float G4 = red[1][0] + red[1][1] + red[1][2] + red[1][3];
        float P4 = red[2][0] + red[2][1] + red[2][2] + red[2][3];
        float Se = S4 + 256.0f * EPS;
        float A = 0.5f * (stirling_lgamma(Se) - G4) + 0.25f * P4;
        *(float4*)sc = make_float4(S4, A, stirling_digamma(Se), 0.0f);
    }
}

// 16x16 pair tile per block. d-loop split in two 128-wide phases so LDS is
// 32 KiB (4 arrays x 16 rows x 128 f32) -> 5 blocks/CU. XOR-(row&7) float4
// column swizzle kills stride-512B bank conflicts.
__global__ __launch_bounds__(256) void jsd_pairs(
    const float* __restrict__ va, const float* __restrict__ ta,
    const float* __restrict__ dgv, const float* __restrict__ dgt,
    const float* __restrict__ rv,  const float* __restrict__ rt,
    float* __restrict__ out)
{
    __shared__ float vs[16 * 128];
    __shared__ float ts[16 * 128];
    __shared__ float gv[16 * 128];
    __shared__ float gt[16 * 128];

    const int tid = threadIdx.x;
    const int j0 = blockIdx.x * 16;      // v rows (output cols)
    const int i0 = blockIdx.y * 16;      // t rows (output rows)

    const int tj = tid & 15;
    const int ti = tid >> 4;
    const int swv = tj & 7;
    const int swt = ti & 7;

    float accP0 = 0.0f, accP1 = 0.0f, accL = 0.0f;
    float xvt0 = 0.0f, xvt1 = 0.0f, xtv0 = 0.0f, xtv1 = 0.0f;

    for (int h = 0; h < 2; ++h) {
        if (h) __syncthreads();          // all reads of phase-0 LDS done
        #pragma unroll
        for (int k = 0; k < 2; ++k) {
            int q   = tid + (k << 8);    // 0..511
            int row = q >> 5;            // 0..15
            int c   = q & 31;            // float4 col 0..31
            int cs  = c ^ (row & 7);
            int goff = h * 128 + (c << 2);
            float4 a = *(const float4*)(va  + (j0 + row) * D + goff);
            float4 b = *(const float4*)(dgv + (j0 + row) * D + goff);
            float4 e = *(const float4*)(ta  + (i0 + row) * D + goff);
            float4 f = *(const float4*)(dgt + (i0 + row) * D + goff);
            *(float4*)(vs + row * 128 + (cs << 2)) = a;
            *(float4*)(gv + row * 128 + (cs << 2)) = b;
            *(float4*)(ts + row * 128 + (cs << 2)) = e;
            *(float4*)(gt + row * 128 + (cs << 2)) = f;
        }
        __syncthreads();

        const float* vrow = vs + tj * 128;
        const float* grow = gv + tj * 128;
        const float* trow = ts + ti * 128;
        const float* hrow = gt + ti * 128;

        #pragma unroll 4
        for (int c = 0; c < 32; ++c) {
            int cv = (c ^ swv) << 2;
            int ct = (c ^ swt) << 2;
            float4 v4 = *(const float4*)(vrow + cv);
            float4 g4 = *(const float4*)(grow + cv);
            float4 t4 = *(const float4*)(trow + ct);
            float4 h4 = *(const float4*)(hrow + ct);

            float m0 = fmaf(0.5f, v4.x + t4.x, EPS);
            float m1 = fmaf(0.5f, v4.y + t4.y, EPS);
            float m2 = fmaf(0.5f, v4.z + t4.z, EPS);
            float m3 = fmaf(0.5f, v4.w + t4.w, EPS);

            float w0 = m0 * (m0 + 1.0f);
            float w1 = m1 * (m1 + 1.0f);
            float w2 = m2 * (m2 + 1.0f);
            float w3 = m3 * (m3 + 1.0f);
            accL += __log2f((w0 * w1) * (w2 * w3));   // one v_log per 4 elems

            float s0 = m0 - 0.5f, s1 = m1 - 0.5f, s2 = m2 - 0.5f, s3 = m3 - 0.5f;
            accP0 = fmaf(lgamma_poly(s0), s0, accP0);
            accP1 = fmaf(lgamma_poly(s1), s1, accP1);
            accP0 = fmaf(lgamma_poly(s2), s2, accP0);
            accP1 = fmaf(lgamma_poly(s3), s3, accP1);

            xvt0 = fmaf(t4.x, g4.x, xvt0); xvt1 = fmaf(t4.y, g4.y, xvt1);
            xvt0 = fmaf(t4.z, g4.z, xvt0); xvt1 = fmaf(t4.w, g4.w, xvt1);
            xtv0 = fmaf(v4.x, h4.x, xtv0); xtv1 = fmaf(v4.y, h4.y, xtv1);
            xtv0 = fmaf(v4.z, h4.z, xtv0); xtv1 = fmaf(v4.w, h4.w, xtv1);
        }
    }

    const int j = j0 + tj, i = i0 + ti;
    float4 RJ = *(const float4*)(rv + j * 4);
    float4 RI = *(const float4*)(rt + i * 4);
    float Sv = RJ.x, Av = RJ.y, dgSv = RJ.z;
    float St = RI.x, At = RI.y, dgSt = RI.z;

    // sum lgamma(m_d) = accP + 256*C0 - ln2 * sum log2(w)
    float accg = (accP0 + accP1) + 256.0f * C0 - LN2 * accL;
    float Sm = fmaf(0.5f, Sv + St, 256.0f * EPS);
    float jsd = accg - stirling_lgamma(Sm) + Av + At
              + 0.25f * ((Sv - St) * (dgSt - dgSv) - ((xvt0 + xvt1) + (xtv0 + xtv1)));

    out[i * 512 + j] = 1.0f - jsd;
}

extern "C" void kernel_launch(void* const* d_in, const int* in_sizes, int n_in,
                              void* d_out, int out_size, void* d_ws, size_t ws_size,
                              hipStream_t stream) {
    const float* va = (const float*)d_in[0];
    const float* ta = (const float*)d_in[1];
    float* ws  = (float*)d_ws;
    float* dgv = ws;
    float* dgt = ws + NV * D;
    float* rv  = ws + (NV + NT) * D;
    float* rt  = rv + NV * 4;
    float* out = (float*)d_out;

    row_stats<<<NV + NT, 256, 0, stream>>>(va, ta, dgv, dgt, rv, rt);
    jsd_pairs<<<dim3(32, 32), 256, 0, stream>>>(va, ta, dgv, dgt, rv, rt, out);
}

// Round 4
// 80.605 us; speedup vs baseline: 1.7532x; 1.0622x over previous
//
#include <hip/hip_runtime.h>

#define D 256
#define NV 512
#define NT 512
#define EPS 1e-8f
#define HALF_EPS 5e-9f
#define LN2 0.69314718055994531f

// Taylor of lgamma(x) at 2.5 (s = x - 2.5). Deg-4 here: |trunc| <= 9.4e-5 on s in [-.5,.5].
// Used as lgamma(m) = poly(s=m-0.5) - ln(m*(m+1)), m in (0, 1].
#define C0 0.28468287047291920f
#define C1 0.70315664064524320f
#define C2 0.24517887805011740f
#define C3 (-0.03936734194028790f)
#define C4 0.00932941036738560f
// deg-6 tail kept for the row_stats path (cheap there)
#define C5 (-0.00261463332905590f)
#define C6 0.00080356830356760f

__device__ __forceinline__ float rcpf(float x) { return __builtin_amdgcn_rcpf(x); }

__device__ __forceinline__ float stirling_lgamma(float y) { // y >= 4
    float r = rcpf(y), r2 = r * r;
    float ln = LN2 * __log2f(y);
    return (y - 0.5f) * ln - y + 0.91893853320467f
         + r * (0.08333333333f - 0.00277777778f * r2);
}

__device__ __forceinline__ float stirling_digamma(float y) { // y >= 4
    float r = rcpf(y), r2 = r * r;
    return LN2 * __log2f(y) - 0.5f * r - r2 * (0.08333333333f - 0.00833333333f * r2);
}

// One block per row. Writes psi row + packed float4 [S, A, dgS, 0] where
// A = 0.5*(lgamma(S') - sum lgamma(x')) + 0.25*sum(raw*psi) + 0.25*EPS*sum(psi)
// (the EPS term pre-corrects the half-scaled dot products in jsd_pairs).
__global__ __launch_bounds__(256) void row_stats(
    const float* __restrict__ va, const float* __restrict__ ta,
    float* __restrict__ dgv, float* __restrict__ dgt,
    float* __restrict__ rv,  float* __restrict__ rt)
{
    int r = blockIdx.x;
    const float* row; float* dgrow; float* sc;
    if (r < NV) { row = va + r * D; dgrow = dgv + r * D; sc = rv + r * 4; }
    else { int q = r - NV; row = ta + q * D; dgrow = dgt + q * D; sc = rt + q * 4; }

    int d = threadIdx.x;
    float raw = row[d];
    float x = raw + EPS;

    // digamma(x) = psi(x+4) - 4 poles
    float y = x + 4.0f;
    float ry = rcpf(y), ry2 = ry * ry;
    float psi = LN2 * __log2f(y) - 0.5f * ry - ry2 * (0.08333333333f - 0.00833333333f * ry2);
    psi -= rcpf(x) + rcpf(x + 1.0f) + rcpf(x + 2.0f) + rcpf(x + 3.0f);
    dgrow[d] = psi;

    // lgamma(x), deg-6 (cheap here, run once per input element)
    float s = x - 0.5f;
    float q6 = fmaf(C6, s, C5);
    q6 = fmaf(q6, s, C4); q6 = fmaf(q6, s, C3); q6 = fmaf(q6, s, C2); q6 = fmaf(q6, s, C1);
    float g = fmaf(q6, s, C0) - LN2 * __log2f(x * (x + 1.0f));

    float S = raw, G = g, P = raw * psi, W = psi;
    #pragma unroll
    for (int off = 32; off > 0; off >>= 1) {
        S += __shfl_down(S, off, 64);
        G += __shfl_down(G, off, 64);
        P += __shfl_down(P, off, 64);
        W += __shfl_down(W, off, 64);
    }
    __shared__ float red[4][4];
    int wid = d >> 6, lane = d & 63;
    if (lane == 0) { red[0][wid] = S; red[1][wid] = G; red[2][wid] = P; red[3][wid] = W; }
    __syncthreads();
    if (d == 0) {
        float S4 = red[0][0] + red[0][1] + red[0][2] + red[0][3];
        float G4 = red[1][0] + red[1][1] + red[1][2] + red[1][3];
        float P4 = red[2][0] + red[2][1] + red[2][2] + red[2][3];
        float W4 = red[3][0] + red[3][1] + red[3][2] + red[3][3];
        float Se = S4 + 256.0f * EPS;
        float A = 0.5f * (stirling_lgamma(Se) - G4) + 0.25f * P4 + (0.25f * EPS) * W4;
        *(float4*)sc = make_float4(S4, A, stirling_digamma(Se), 0.0f);
    }
}

// 16x16 pair tile per block, D split into 4 width-64 phases -> 16 KiB LDS.
// LDS holds vh = 0.5*(v+EPS), th = 0.5*(t+EPS) (so m = vh+th, 1 add) plus psi
// rows. XOR-(row&7) float4-column swizzle avoids stride bank conflicts.
__global__ __launch_bounds__(256) void jsd_pairs(
    const float* __restrict__ va, const float* __restrict__ ta,
    const float* __restrict__ dgv, const float* __restrict__ dgt,
    const float* __restrict__ rv,  const float* __restrict__ rt,
    float* __restrict__ out)
{
    __shared__ float vs[16 * 64];
    __shared__ float ts[16 * 64];
    __shared__ float gv[16 * 64];
    __shared__ float gt[16 * 64];

    const int tid = threadIdx.x;
    const int j0 = blockIdx.x * 16;      // v rows (output cols)
    const int i0 = blockIdx.y * 16;      // t rows (output rows)

    const int tj = tid & 15;
    const int ti = tid >> 4;
    const int swv = tj & 7;
    const int swt = ti & 7;

    // staging indices: one float4 per array per thread per phase
    const int srow = tid >> 4;           // 0..15
    const int sc_  = tid & 15;           // float4 col 0..15
    const int scs  = sc_ ^ (srow & 7);

    float accP0 = 0.0f, accP1 = 0.0f, accL = 0.0f;
    float xvt0 = 0.0f, xvt1 = 0.0f, xtv0 = 0.0f, xtv1 = 0.0f;

    for (int h = 0; h < 4; ++h) {
        if (h) __syncthreads();
        {
            int goff = h * 64 + (sc_ << 2);
            float4 a = *(const float4*)(va  + (j0 + srow) * D + goff);
            float4 e = *(const float4*)(ta  + (i0 + srow) * D + goff);
            float4 b = *(const float4*)(dgv + (j0 + srow) * D + goff);
            float4 f = *(const float4*)(dgt + (i0 + srow) * D + goff);
            a.x = fmaf(0.5f, a.x, HALF_EPS); a.y = fmaf(0.5f, a.y, HALF_EPS);
            a.z = fmaf(0.5f, a.z, HALF_EPS); a.w = fmaf(0.5f, a.w, HALF_EPS);
            e.x = fmaf(0.5f, e.x, HALF_EPS); e.y = fmaf(0.5f, e.y, HALF_EPS);
            e.z = fmaf(0.5f, e.z, HALF_EPS); e.w = fmaf(0.5f, e.w, HALF_EPS);
            *(float4*)(vs + srow * 64 + (scs << 2)) = a;
            *(float4*)(ts + srow * 64 + (scs << 2)) = e;
            *(float4*)(gv + srow * 64 + (scs << 2)) = b;
            *(float4*)(gt + srow * 64 + (scs << 2)) = f;
        }
        __syncthreads();

        const float* vrow = vs + tj * 64;
        const float* grow = gv + tj * 64;
        const float* trow = ts + ti * 64;
        const float* hrow = gt + ti * 64;

        #pragma unroll
        for (int c = 0; c < 16; ++c) {
            int cv = (c ^ swv) << 2;
            int ct = (c ^ swt) << 2;
            float4 v4 = *(const float4*)(vrow + cv);
            float4 g4 = *(const float4*)(grow + cv);
            float4 t4 = *(const float4*)(trow + ct);
            float4 h4 = *(const float4*)(hrow + ct);

            float m0 = v4.x + t4.x, m1 = v4.y + t4.y;
            float m2 = v4.z + t4.z, m3 = v4.w + t4.w;

            float w0 = fmaf(m0, m0, m0), w1 = fmaf(m1, m1, m1);
            float w2 = fmaf(m2, m2, m2), w3 = fmaf(m3, m3, m3);
            accL += __log2f((w0 * w1) * (w2 * w3));   // one trans per 4 elems

            float s0 = m0 - 0.5f, s1 = m1 - 0.5f, s2 = m2 - 0.5f, s3 = m3 - 0.5f;
            float q0 = fmaf(C4, s0, C3); q0 = fmaf(q0, s0, C2); q0 = fmaf(q0, s0, C1);
            float q1 = fmaf(C4, s1, C3); q1 = fmaf(q1, s1, C2); q1 = fmaf(q1, s1, C1);
            float q2 = fmaf(C4, s2, C3); q2 = fmaf(q2, s2, C2); q2 = fmaf(q2, s2, C1);
            float q3 = fmaf(C4, s3, C3); q3 = fmaf(q3, s3, C2); q3 = fmaf(q3, s3, C1);
            accP0 = fmaf(q0, s0, accP0); accP1 = fmaf(q1, s1, accP1);
            accP0 = fmaf(q2, s2, accP0); accP1 = fmaf(q3, s3, accP1);

            xvt0 = fmaf(t4.x, g4.x, xvt0); xvt1 = fmaf(t4.y, g4.y, xvt1);
            xvt0 = fmaf(t4.z, g4.z, xvt0); xvt1 = fmaf(t4.w, g4.w, xvt1);
            xtv0 = fmaf(v4.x, h4.x, xtv0); xtv1 = fmaf(v4.y, h4.y, xtv1);
            xtv0 = fmaf(v4.z, h4.z, xtv0); xtv1 = fmaf(v4.w, h4.w, xtv1);
        }
    }

    const int j = j0 + tj, i = i0 + ti;
    float4 RJ = *(const float4*)(rv + j * 4);
    float4 RI = *(const float4*)(rt + i * 4);
    float Sv = RJ.x, Av = RJ.y, dgSv = RJ.z;
    float St = RI.x, At = RI.y, dgSt = RI.z;

    // sum lgamma(m_d) = accP + 256*C0 - ln2 * accL
    float accg = (accP0 + accP1) + 256.0f * C0 - LN2 * accL;
    float Sm = Sv + St;                       // (Sv+St) + 256*EPS via halves? Sv,St raw sums
    Sm = fmaf(0.5f, Sm, 256.0f * EPS);
    // dots were computed with half-scaled inputs: true 0.25*(xvt+xtv) = 0.5*(xvt'+xtv') - EPS-part (folded in A)
    float jsd = accg - stirling_lgamma(Sm) + Av + At
              - 0.5f * ((xvt0 + xvt1) + (xtv0 + xtv1))
              + 0.25f * (Sv - St) * (dgSt - dgSv);

    out[i * 512 + j] = 1.0f - jsd;
}

extern "C" void kernel_launch(void* const* d_in, const int* in_sizes, int n_in,
                              void* d_out, int out_size, void* d_ws, size_t ws_size,
                              hipStream_t stream) {
    const float* va = (const float*)d_in[0];
    const float* ta = (const float*)d_in[1];
    float* ws  = (float*)d_ws;
    float* dgv = ws;
    float* dgt = ws + NV * D;
    float* rv  = ws + (NV + NT) * D;
    float* rt  = rv + NV * 4;
    float* out = (float*)d_out;

    row_stats<<<NV + NT, 256, 0, stream>>>(va, ta, dgv, dgt, rv, rt);
    jsd_pairs<<<dim3(32, 32), 256, 0, stream>>>(va, ta, dgv, dgt, rv, rt, out);
}